// Round 5
// baseline (202.046 us; speedup 1.0000x reference)
//
#include <hip/hip_runtime.h>
#include <hip/hip_bf16.h>

// TDNN as GEMM, faithful m201-style 256x256 8-phase schedule (T1+T2+T3+T4+T5).
//   out[m,o] = relu(bias[o] + sum_kk A[m,kk]*W[kk,o])
//   A[m,kk] = x[b, t+kw, c] (contiguous 2560-elem slice), W[kk,o] = kernel[o,c,kw]
// 2 K-tiles (BK=64 each) per loop iter, 8 phases, 1 half-tile stage per phase,
// vmcnt(6) at phases 4/8 only, 12/8/4/0 ds_read spread, setprio on MFMA clusters.

#define BATCH 64
#define SEQ   1000
#define CIN   512
#define COUT  512
#define TOUT  996
#define KTOT  2560
#define MTOT  63744
#define NKT   40            // K-tiles of 64
#define MT    249           // MTOT/256
#define NT    2             // COUT/256
#define NWG   (MT*NT)       // 498

typedef __bf16 bf16x8 __attribute__((ext_vector_type(8)));
typedef float  f32x4  __attribute__((ext_vector_type(4)));

__device__ __forceinline__ void gload_lds16(const void* g, void* l) {
  __builtin_amdgcn_global_load_lds(
      (const __attribute__((address_space(1))) void*)g,
      (__attribute__((address_space(3))) void*)l, 16, 0, 0);
}

#define BAR()    __builtin_amdgcn_s_barrier()
#define VM6()    asm volatile("s_waitcnt vmcnt(6)" ::: "memory")
#define VM0()    asm volatile("s_waitcnt vmcnt(0)" ::: "memory")
#define LGKM0()  asm volatile("s_waitcnt lgkmcnt(0)" ::: "memory")
#define LGKM8()  asm volatile("s_waitcnt lgkmcnt(8)" ::: "memory")
#define PRIO(x)  __builtin_amdgcn_s_setprio(x)
#define MFMA(d, x, y) d = __builtin_amdgcn_mfma_f32_16x16x32_bf16(x, y, d, 0, 0, 0)

// ---- x fp32 -> bf16 ----
__global__ void cvt_x_kernel(const float* __restrict__ x, __bf16* __restrict__ xb, int n) {
  int i = (blockIdx.x * blockDim.x + threadIdx.x) * 8;
  if (i >= n) return;
  float4 f0 = *(const float4*)(x + i);
  float4 f1 = *(const float4*)(x + i + 4);
  bf16x8 v;
  v[0] = (__bf16)f0.x; v[1] = (__bf16)f0.y; v[2] = (__bf16)f0.z; v[3] = (__bf16)f0.w;
  v[4] = (__bf16)f1.x; v[5] = (__bf16)f1.y; v[6] = (__bf16)f1.z; v[7] = (__bf16)f1.w;
  *(bf16x8*)(xb + i) = v;
}

// ---- kernel [O][C][KW] fp32 -> Wt [O][KTOT] bf16, Wt[o][kw*512+c] ----
__global__ void cvt_w_kernel(const float* __restrict__ k, __bf16* __restrict__ wt) {
  int idx = blockIdx.x * blockDim.x + threadIdx.x;
  if (idx >= COUT * KTOT) return;
  int o  = idx / KTOT;
  int r  = idx - o * KTOT;
  int kw = r >> 9;
  int c  = r & 511;
  wt[idx] = (__bf16)k[(o * CIN + c) * 5 + kw];
}

// ---- half-tile stages: 2 x gload_lds(16B)/thread each ----
// A half h covers rows {h*64..h*64+63} U {128+h*64..128+h*64+63} (quadrant union)
#define STAGE_AH(buf, h, kt) do { \
    char* d_ = (char*)Ab + ((buf) << 15); \
    gload_lds16(Xb + offA##h##0 + (kt) * 64, d_ + dstA##h##0); \
    gload_lds16(Xb + offA##h##1 + (kt) * 64, d_ + dstA##h##1); } while (0)
// B half h covers row stripes {h*32+s*64 .. +31 : s=0..3}
#define STAGE_BH(buf, h, kt) do { \
    char* d_ = (char*)Bb + ((buf) << 15); \
    gload_lds16(Wt + offB##h##0 + (kt) * 64, d_ + dstB##h##0); \
    gload_lds16(Wt + offB##h##1 + (kt) * 64, d_ + dstB##h##1); } while (0)

// register-fragment reads (read-side XOR matches pre-swizzled source)
#define RDA4(dst, base, mi0) do { \
    _Pragma("unroll") \
    for (int mi_ = 0; mi_ < 4; ++mi_) { \
      dst[mi_][0] = *(const bf16x8*)((base) + ((mi0) + mi_) * 2048 + off0); \
      dst[mi_][1] = *(const bf16x8*)((base) + ((mi0) + mi_) * 2048 + off1); } } while (0)
#define RDB2(dst, base, nj0) do { \
    _Pragma("unroll") \
    for (int nj_ = 0; nj_ < 2; ++nj_) { \
      dst[nj_][0] = *(const bf16x8*)((base) + ((nj0) + nj_) * 2048 + off0); \
      dst[nj_][1] = *(const bf16x8*)((base) + ((nj0) + nj_) * 2048 + off1); } } while (0)

// 16-MFMA quadrant cluster
#define QUAD(r0, c0, AF, BF) do { \
    PRIO(1); \
    _Pragma("unroll") \
    for (int mi_ = 0; mi_ < 4; ++mi_) \
      _Pragma("unroll") \
      for (int nj_ = 0; nj_ < 2; ++nj_) { \
        MFMA(acc[(r0) + mi_][(c0) + nj_], AF[mi_][0], BF[nj_][0]); \
        MFMA(acc[(r0) + mi_][(c0) + nj_], AF[mi_][1], BF[nj_][1]); \
      } \
    PRIO(0); } while (0)

__global__ __launch_bounds__(512, 2)
void tdnn_gemm_kernel(const __bf16* __restrict__ Xb, const __bf16* __restrict__ Wt,
                      const float* __restrict__ bias, float* __restrict__ out) {
  __shared__ __bf16 Ab[2][256][64];   // 64 KiB
  __shared__ __bf16 Bb[2][256][64];   // 64 KiB

  const int tid  = threadIdx.x;
  const int wave = tid >> 6;
  const int lane = tid & 63;
  const int wr = wave >> 2;          // 0..1 : 128-row band
  const int wc = wave & 3;           // 0..3 : 64-col band

  // bijective XCD swizzle: 498 = 8*62 + 2
  int bid = blockIdx.x;
  int xcd = bid & 7, jj = bid >> 3;
  const int q = NWG >> 3, r = NWG & 7;
  int swz = (xcd < r ? xcd * (q + 1) : r * (q + 1) + (xcd - r) * q) + jj;
  const int m0 = (swz >> 1) * 256;
  const int n0 = (swz & 1) * 256;

  // ---- staging offsets (pre-swizzled global source, linear LDS dest)
  const int tq = tid >> 3;           // 0..63
  const int t8 = tid & 7;
  const int ce = (t8 ^ (tq & 7)) << 3;   // swizzled col offset, elems

  int offA00, offA01, offA10, offA11, dstA00, dstA01, dstA10, dstA11;
  int offB00, offB01, offB10, offB11, dstB00, dstB01, dstB10, dstB11;
  {
    int rr, m, b, tt;
#define MKA(h, l, A, D) \
    rr = (h) * 64 + (l) * 128 + tq; \
    m = m0 + rr; b = m / TOUT; tt = m - b * TOUT; \
    A = (b * SEQ + tt) * CIN + ce; \
    D = rr * 128 + (t8 << 4);
    MKA(0, 0, offA00, dstA00)
    MKA(0, 1, offA01, dstA01)
    MKA(1, 0, offA10, dstA10)
    MKA(1, 1, offA11, dstA11)
#undef MKA
#define MKB(h, l, B, D) \
    rr = (h) * 32 + ((l) * 2 + (tid >> 8)) * 64 + (tq & 31); \
    B = (n0 + rr) * KTOT + ce; \
    D = rr * 128 + (t8 << 4);
    MKB(0, 0, offB00, dstB00)
    MKB(0, 1, offB01, dstB01)
    MKB(1, 0, offB10, dstB10)
    MKB(1, 1, offB11, dstB11)
#undef MKB
  }

  // ---- fragment read geometry
  const int frow = lane & 15;
  const int fkb  = (lane >> 4) << 4;        // 0,16,32,48 bytes
  const int xorv = (frow & 7) << 4;
  const int off0 = fkb ^ xorv;
  const int off1 = (64 + fkb) ^ xorv;
  const char* Ab0 = (const char*)Ab + (wr * 128 + frow) * 128;
  const char* Bb0 = (const char*)Bb + (wc * 64 + frow) * 128;

  f32x4 acc[8][4];
  const f32x4 z = {0.f, 0.f, 0.f, 0.f};
#pragma unroll
  for (int i = 0; i < 8; i++)
#pragma unroll
    for (int j = 0; j < 4; j++) acc[i][j] = z;

  bf16x8 a03[4][2], a47[4][2], b01[2][2], b23[2][2];

  // ---- prologue: tile0 all 4 halves + tile1 {A-h0,A-h1,B-h0} = 14 loads
  STAGE_AH(0, 0, 0); STAGE_AH(0, 1, 0);
  STAGE_BH(0, 0, 0); STAGE_BH(0, 1, 0);
  STAGE_AH(1, 0, 1); STAGE_AH(1, 1, 1);
  STAGE_BH(1, 0, 1);
  VM6();     // drains tile0's 8 loads; keeps tile1's 6 in flight
  BAR();

  for (int T0 = 0; T0 < NKT; T0 += 2) {
    const int T1 = T0 + 1;
    const bool s2a = (T0 + 2 < NKT);
    const bool s2b = (T1 + 2 < NKT);
    const char* Ac = Ab0;            // buf0 (tiles T0 even)
    const char* Bc = Bb0;
    const char* Ao = Ab0 + 32768;    // buf1 (tiles T1 odd)
    const char* Bo = Bb0 + 32768;

    // -- ph1: read a03,b01 (T0); stage B(T1)h1; Q1
    RDA4(a03, Ac, 0); RDB2(b01, Bc, 0);
    STAGE_BH(1, 1, T1);
    LGKM8(); BAR(); LGKM0();
    QUAD(0, 0, a03, b01);
    BAR();

    // -- ph2: read a47 (T0); stage A(T0+2)h0 -> buf0; Q2
    RDA4(a47, Ac, 4);
    if (s2a) STAGE_AH(0, 0, T0 + 2);
    BAR(); LGKM0();
    QUAD(4, 0, a47, b01);
    BAR();

    // -- ph3: read b23 (T0); stage A(T0+2)h1; Q3
    RDB2(b23, Bc, 2);
    if (s2a) STAGE_AH(0, 1, T0 + 2);
    BAR(); LGKM0();
    QUAD(0, 2, a03, b23);
    BAR();

    // -- ph4: stage B(T0+2)h0; counted vmcnt (drains through B(T1)h1); Q4
    if (s2a) { STAGE_BH(0, 0, T0 + 2); VM6(); } else { VM0(); }
    BAR();
    QUAD(4, 2, a47, b23);
    BAR();

    // -- ph5: read a03,b01 (T1, buf1); stage B(T0+2)h1; Q1'
    RDA4(a03, Ao, 0); RDB2(b01, Bo, 0);
    if (s2a) STAGE_BH(0, 1, T0 + 2);
    LGKM8(); BAR(); LGKM0();
    QUAD(0, 0, a03, b01);
    BAR();

    // -- ph6: read a47 (T1); stage A(T1+2)h0 -> buf1; Q2'
    RDA4(a47, Ao, 4);
    if (s2b) STAGE_AH(1, 0, T1 + 2);
    BAR(); LGKM0();
    QUAD(4, 0, a47, b01);
    BAR();

    // -- ph7: read b23 (T1); stage A(T1+2)h1; Q3'
    RDB2(b23, Bo, 2);
    if (s2b) STAGE_AH(1, 1, T1 + 2);
    BAR(); LGKM0();
    QUAD(0, 2, a03, b23);
    BAR();

    // -- ph8: stage B(T1+2)h0; counted vmcnt (drains through B(T0+2)h1); Q4'
    if (s2b) { STAGE_BH(1, 0, T1 + 2); VM6(); }
    BAR();
    QUAD(4, 2, a47, b23);
    BAR();
  }

  // ---- epilogue: bias + relu + store. C/D map: col=lane&15, row=(lane>>4)*4+reg
  const int ccol = lane & 15;
  const int crow = (lane >> 4) * 4;
  float bv[4];
#pragma unroll
  for (int nj = 0; nj < 4; ++nj)
    bv[nj] = bias[n0 + wc * 64 + nj * 16 + ccol];

#pragma unroll
  for (int mi = 0; mi < 8; ++mi) {
    const int mrow = m0 + wr * 128 + mi * 16 + crow;
#pragma unroll
    for (int nj = 0; nj < 4; ++nj) {
      const int ocol = n0 + wc * 64 + nj * 16 + ccol;
#pragma unroll
      for (int j = 0; j < 4; ++j) {
        float v = acc[mi][nj][j] + bv[nj];
        v = v > 0.f ? v : 0.f;
        out[(size_t)(mrow + j) * COUT + ocol] = v;
      }
    }
  }
}

extern "C" void kernel_launch(void* const* d_in, const int* in_sizes, int n_in,
                              void* d_out, int out_size, void* d_ws, size_t ws_size,
                              hipStream_t stream) {
  const float* x      = (const float*)d_in[0];   // [64,1000,512] fp32
  const float* kernel = (const float*)d_in[1];   // [512,512,5]   fp32
  const float* bias   = (const float*)d_in[2];   // [512]         fp32
  float* out          = (float*)d_out;           // [64,996,512]  fp32

  __bf16* xb = (__bf16*)d_ws;
  __bf16* wt = (__bf16*)((char*)d_ws + (size_t)BATCH * SEQ * CIN * 2);

  const int nx = BATCH * SEQ * CIN;              // 32,768,000
  cvt_x_kernel<<<nx / 8 / 256, 256, 0, stream>>>(x, xb, nx);
  cvt_w_kernel<<<(COUT * KTOT + 255) / 256, 256, 0, stream>>>(kernel, wt);
  tdnn_gemm_kernel<<<NWG, 512, 0, stream>>>(xb, wt, bias, out);
}

// Round 6
// 201.562 us; speedup vs baseline: 1.0024x; 1.0024x over previous
//
#include <hip/hip_runtime.h>
#include <hip/hip_bf16.h>

// TDNN as GEMM: out[m,o] = relu(bias[o] + sum_kk A[m,kk]*W[kk,o])
//   A[m,kk] = x[b, t+kw, c] (contiguous 2560-elem slice of x)
// R6: 128x128 tile, 4 waves (wave-tile 64x64, acc=64), B out of LDS
// (fragment-native Wt2 from L2, reg-prefetched 1 tile ahead), A in 4-buffer
// LDS rotation (64 KiB/block -> 2 blocks/CU for cross-block co-scheduling),
// counted vmcnt + 1 barrier per K-tile, proven 0-conflict XOR swizzle.

#define BATCH 64
#define SEQ   1000
#define CIN   512
#define COUT  512
#define TOUT  996
#define KTOT  2560
#define MTOT  63744
#define NKT   40            // K-tiles of 64
#define MT    498           // MTOT/128
#define NT    4             // COUT/128
#define NWG   (MT*NT)       // 1992 = 8*249

typedef __bf16 bf16x8 __attribute__((ext_vector_type(8)));
typedef float  f32x4  __attribute__((ext_vector_type(4)));

__device__ __forceinline__ void gload_lds16(const void* g, void* l) {
  __builtin_amdgcn_global_load_lds(
      (const __attribute__((address_space(1))) void*)g,
      (__attribute__((address_space(3))) void*)l, 16, 0, 0);
}

#define BAR()    __builtin_amdgcn_s_barrier()
#define VM12()   asm volatile("s_waitcnt vmcnt(12)" ::: "memory")
#define VM8()    asm volatile("s_waitcnt vmcnt(8)"  ::: "memory")
#define VM4()    asm volatile("s_waitcnt vmcnt(4)"  ::: "memory")
#define PRIO(x)  __builtin_amdgcn_s_setprio(x)
#define SCHED0() __builtin_amdgcn_sched_barrier(0)
#define MFMA(d, x, y) d = __builtin_amdgcn_mfma_f32_16x16x32_bf16(x, y, d, 0, 0, 0)

// ---- x fp32 -> bf16 ----
__global__ void cvt_x_kernel(const float* __restrict__ x, __bf16* __restrict__ xb, int n) {
  int i = (blockIdx.x * blockDim.x + threadIdx.x) * 8;
  if (i >= n) return;
  float4 f0 = *(const float4*)(x + i);
  float4 f1 = *(const float4*)(x + i + 4);
  bf16x8 v;
  v[0] = (__bf16)f0.x; v[1] = (__bf16)f0.y; v[2] = (__bf16)f0.z; v[3] = (__bf16)f0.w;
  v[4] = (__bf16)f1.x; v[5] = (__bf16)f1.y; v[6] = (__bf16)f1.z; v[7] = (__bf16)f1.w;
  *(bf16x8*)(xb + i) = v;
}

// ---- kernel [O][C][KW] fp32 -> Wt2 fragment-native bf16 ----
// elem idx = ((ks*32 + ob)*64 + l)*8 + j
//   col o = ob*16 + (l&15); k = ks*32 + ((l>>4)&3)*8 + j; c = k&511; kw = k>>9
__global__ void cvt_w_kernel(const float* __restrict__ k, __bf16* __restrict__ wt) {
  int idx = blockIdx.x * blockDim.x + threadIdx.x;   // 1,310,720
  if (idx >= 80 * 32 * 512) return;
  int j  = idx & 7;
  int l  = (idx >> 3) & 63;
  int t1 = idx >> 9;
  int ob = t1 & 31;
  int ks = t1 >> 5;
  int o  = ob * 16 + (l & 15);
  int kk = ks * 32 + ((l >> 4) & 3) * 8 + j;
  int c  = kk & 511, kw = kk >> 9;
  wt[idx] = (__bf16)k[(o * CIN + c) * 5 + kw];
}

// stage one A K-tile (128 rows x 64 bf16 = 16 KiB): 4 x gload_lds16/thread
#define STAGE(buf, kt) do { \
    char* d_ = (char*)Ab + ((buf) << 14); \
    gload_lds16(Xb + offA0 + (kt) * 64, d_ + dof0); \
    gload_lds16(Xb + offA1 + (kt) * 64, d_ + dof1); \
    gload_lds16(Xb + offA2 + (kt) * 64, d_ + dof2); \
    gload_lds16(Xb + offA3 + (kt) * 64, d_ + dof3); } while (0)

// load next-tile B fragments from global (L2-resident), 8 x dwordx4
#define LOADB(bn, Tn) do { \
    const char* p_ = Wglob + (size_t)(Tn) * 65536; \
    bn[0][0] = *(const bf16x8*)(p_ +     0); bn[0][1] = *(const bf16x8*)(p_ + 32768); \
    bn[1][0] = *(const bf16x8*)(p_ +  1024); bn[1][1] = *(const bf16x8*)(p_ + 33792); \
    bn[2][0] = *(const bf16x8*)(p_ +  2048); bn[2][1] = *(const bf16x8*)(p_ + 34816); \
    bn[3][0] = *(const bf16x8*)(p_ +  3072); bn[3][1] = *(const bf16x8*)(p_ + 35840); } while (0)

// one K-tile: prefetch B(T+1)->regs, stage A(T+2)->LDS, 8 ds_read + 32 MFMA,
// counted vmcnt + single barrier.
#define TILE(T, bc, bn) do { \
    const bool s1_ = (T) + 1 < NKT, s2_ = (T) + 2 < NKT; \
    if (s1_) LOADB(bn, (T) + 1); \
    if (s2_) STAGE(((T) + 2) & 3, (T) + 2); \
    const char* Ac_ = Aw + (((T) & 3) << 14); \
    bf16x8 a_[4][2]; \
    _Pragma("unroll") \
    for (int mi = 0; mi < 4; ++mi) { \
      a_[mi][0] = *(const bf16x8*)(Ac_ + mi * 2048 + off0); \
      a_[mi][1] = *(const bf16x8*)(Ac_ + mi * 2048 + off1); \
    } \
    PRIO(1); \
    _Pragma("unroll") \
    for (int mi = 0; mi < 4; ++mi) \
      _Pragma("unroll") \
      for (int nj = 0; nj < 4; ++nj) { \
        MFMA(acc[mi][nj], a_[mi][0], bc[nj][0]); \
        MFMA(acc[mi][nj], a_[mi][1], bc[nj][1]); \
      } \
    PRIO(0); \
    SCHED0(); \
    if (s2_) { VM12(); } else if (s1_) { VM8(); } \
    if (s1_) BAR(); \
  } while (0)

__global__ __launch_bounds__(256, 2)
void tdnn_gemm_kernel(const __bf16* __restrict__ Xb, const __bf16* __restrict__ Wt2,
                      const float* __restrict__ bias, float* __restrict__ out) {
  // A only: 4 rotating K-tile buffers x 128 rows x 64 bf16 = 64 KiB
  __shared__ __bf16 Ab[4][128][64];

  const int tid  = threadIdx.x;
  const int wave = tid >> 6;
  const int lane = tid & 63;
  const int wr = wave >> 1;          // 0..1 : 64-row band
  const int wc = wave & 1;           // 0..1 : 64-col band

  // bijective XCD swizzle: 1992 = 8*249; consecutive swz share the A-panel
  int bid = blockIdx.x;
  int swz = (bid & 7) * 249 + (bid >> 3);
  const int m0 = (swz >> 2) * 128;
  const int n0 = (swz & 3) * 128;

  // ---- A staging offsets (pre-swizzled global source, linear LDS dest)
  int offA0, offA1, offA2, offA3, dof0, dof1, dof2, dof3;
  {
    int rr, ce, m, b, tt;
#define MKOFF(l, A, D) \
    rr = (l) * 32 + (tid >> 3); \
    ce = (((tid & 7) ^ (rr & 7)) << 3); \
    D  = ((l) * 256 + tid) * 16; \
    m = m0 + rr; b = m / TOUT; tt = m - b * TOUT; \
    A = (b * SEQ + tt) * CIN + ce;
    MKOFF(0, offA0, dof0)
    MKOFF(1, offA1, dof1)
    MKOFF(2, offA2, dof2)
    MKOFF(3, offA3, dof3)
#undef MKOFF
  }

  // ---- fragment read geometry (A from LDS, T2 read-side XOR)
  const int frow = lane & 15;
  const int fkb  = (lane >> 4) << 4;        // 0,16,32,48 bytes
  const int xorv = (frow & 7) << 4;
  const int off0 = fkb ^ xorv;              // k-slice 0
  const int off1 = (64 + fkb) ^ xorv;       // k-slice 1
  const char* Aw = (const char*)Ab + (wr * 64 + frow) * 128;

  // ---- B fragment-native global base for this wave
  const int obW = (n0 >> 4) + wc * 4;
  const char* Wglob = (const char*)Wt2 + obW * 1024 + lane * 16;

  f32x4 acc[4][4];
  const f32x4 z = {0.f, 0.f, 0.f, 0.f};
#pragma unroll
  for (int i = 0; i < 4; i++)
#pragma unroll
    for (int j = 0; j < 4; j++) acc[i][j] = z;

  bf16x8 bA[4][2], bB[4][2];

  // ---- prologue: B(0)->bA, stage A(0)->buf0, A(1)->buf1; drain through A(0)
  LOADB(bA, 0);
  STAGE(0, 0);
  STAGE(1, 1);
  VM4();       // in-order: drains B(0)x8 + A(0)x4, leaves A(1)x4 in flight
  BAR();

  for (int T = 0; T < NKT; T += 2) {
    TILE(T,     bA, bB);
    TILE(T + 1, bB, bA);
  }

  // ---- epilogue: bias + relu + store. C/D map: col=lane&15, row=(lane>>4)*4+reg
  const int ccol = lane & 15;
  const int crow = (lane >> 4) * 4;
  float bv[4];
#pragma unroll
  for (int nj = 0; nj < 4; ++nj)
    bv[nj] = bias[n0 + wc * 64 + nj * 16 + ccol];

#pragma unroll
  for (int mi = 0; mi < 4; ++mi) {
    const int mrow = m0 + wr * 64 + mi * 16 + crow;
#pragma unroll
    for (int nj = 0; nj < 4; ++nj) {
      const int ocol = n0 + wc * 64 + nj * 16 + ccol;
#pragma unroll
      for (int j = 0; j < 4; ++j) {
        float v = acc[mi][nj][j] + bv[nj];
        v = v > 0.f ? v : 0.f;
        out[(size_t)(mrow + j) * COUT + ocol] = v;
      }
    }
  }
}

extern "C" void kernel_launch(void* const* d_in, const int* in_sizes, int n_in,
                              void* d_out, int out_size, void* d_ws, size_t ws_size,
                              hipStream_t stream) {
  const float* x      = (const float*)d_in[0];   // [64,1000,512] fp32
  const float* kernel = (const float*)d_in[1];   // [512,512,5]   fp32
  const float* bias   = (const float*)d_in[2];   // [512]         fp32
  float* out          = (float*)d_out;           // [64,996,512]  fp32

  __bf16* xb  = (__bf16*)d_ws;
  __bf16* wt2 = (__bf16*)((char*)d_ws + (size_t)BATCH * SEQ * CIN * 2);

  const int nx = BATCH * SEQ * CIN;              // 32,768,000
  cvt_x_kernel<<<nx / 8 / 256, 256, 0, stream>>>(x, xb, nx);
  cvt_w_kernel<<<(80 * 32 * 512 + 255) / 256, 256, 0, stream>>>(kernel, wt2);
  tdnn_gemm_kernel<<<NWG, 256, 0, stream>>>(xb, wt2, bias, out);
}